// Round 3
// baseline (403.268 us; speedup 1.0000x reference)
//
#include <hip/hip_runtime.h>
#include <hip/hip_bf16.h>

#define NN 8192      // nodes
#define FIN 512      // in features
#define HD 256       // hidden
#define DD 64        // embedding
#define NE 262144    // edges
#define BCAP 128     // fixed bucket capacity per row (max degree ~60 for this graph; 17-sigma margin)

typedef __bf16 bf16_t;
typedef __bf16 bf16x8 __attribute__((ext_vector_type(8)));
typedef __bf16 bf16x4 __attribute__((ext_vector_type(4)));
typedef float f32x4 __attribute__((ext_vector_type(4)));

// ---------------- fused prep: cast x, transpose W1/W2, zero degree counters ----------------
// grid = 4096 (x) + 512 (W1) + 64 (W2) + 32 (zero deg) blocks of 256
__global__ __launch_bounds__(256) void prep_kernel(const float* __restrict__ x, bf16_t* __restrict__ x_b,
                                                   const float* __restrict__ W1, bf16_t* __restrict__ w1t,
                                                   const float* __restrict__ W2, bf16_t* __restrict__ w2t,
                                                   int* __restrict__ deg) {
    int b = blockIdx.x;
    if (b < 4096) {
        int i = (b * 256 + threadIdx.x) * 4;
        float4 v = *reinterpret_cast<const float4*>(x + i);
        x_b[i + 0] = (bf16_t)v.x;
        x_b[i + 1] = (bf16_t)v.y;
        x_b[i + 2] = (bf16_t)v.z;
        x_b[i + 3] = (bf16_t)v.w;
    } else if (b < 4096 + 512) {
        // W1 [FIN=512, HD=256] -> w1t [HD, FIN];  o = c*512 + r
        int o = (b - 4096) * 256 + threadIdx.x;
        int r = o & 511;
        int c = o >> 9;
        w1t[o] = (bf16_t)W1[r * HD + c];
    } else if (b < 4096 + 512 + 64) {
        // W2 [HD=256, DD=64] -> w2t [DD, HD];  o = c*256 + r
        int o = (b - 4096 - 512) * 256 + threadIdx.x;
        int r = o & 255;
        int c = o >> 8;
        w2t[o] = (bf16_t)W2[r * DD + c];
    } else {
        int o = (b - 4096 - 512 - 64) * 256 + threadIdx.x;
        deg[o] = 0;
    }
}

// ---------------- bucket build (no CSR: fixed stride BCAP per row) ----------------
// (col, val) fused into one int2 -> ONE random 8 B store per edge instead of
// two random 4 B stores into separate arrays (halves random cacheline touches).

__global__ void scatter_edges(const int* __restrict__ rows, const int* __restrict__ cols,
                              const float* __restrict__ vals,
                              int* __restrict__ deg, int2* __restrict__ sedge) {
    int e = blockIdx.x * blockDim.x + threadIdx.x;
    if (e < NE) {
        int r = rows[e];
        int p = atomicAdd(&deg[r], 1);
        int2 pk;
        pk.x = cols[e];
        pk.y = __float_as_int(vals[e]);
        sedge[r * BCAP + p] = pk;
    }
}

// ---------------- SpMM ----------------

// h[r,:] = relu(sum_e val * h0[col,:]); one WAVE per row (4 rows/block).
// Wave covers all 256 features as 64 lanes x bf16x4 (8 B/lane, 512 B/row —
// fully coalesced). Edge (col,val) pairs staged into per-wave LDS with one
// coalesced int2 load (wave-synchronous; per-wave private slice, no barrier),
// then the gather loop unrolls over independent addresses so several gathers
// stay in flight. Broadcast LDS reads (same addr all lanes) are conflict-free.
__global__ __launch_bounds__(256) void spmm_h_kernel(const int* __restrict__ deg,
                                                     const int2* __restrict__ sedge,
                                                     const bf16_t* __restrict__ h0,
                                                     bf16_t* __restrict__ h) {
    int wv = threadIdx.x >> 6;
    int lane = threadIdx.x & 63;
    int r = blockIdx.x * 4 + wv;
    int nd = deg[r];
    int base = r * BCAP;
    __shared__ int2 ecS[4][64];
    float a0 = 0.f, a1 = 0.f, a2 = 0.f, a3 = 0.f;
    for (int e0 = 0; e0 < nd; e0 += 64) {
        int rem = nd - e0;
        if (rem > 64) rem = 64;
        if (lane < rem) ecS[wv][lane] = sedge[base + e0 + lane];
        // wave-private LDS: compiler orders ds_write->ds_read via lgkmcnt
#pragma unroll 4
        for (int e = 0; e < rem; e++) {
            int c = ecS[wv][e].x;
            float v = __int_as_float(ecS[wv][e].y);
            bf16x4 hv = *reinterpret_cast<const bf16x4*>(h0 + (size_t)c * HD + lane * 4);
            a0 += v * (float)hv[0];
            a1 += v * (float)hv[1];
            a2 += v * (float)hv[2];
            a3 += v * (float)hv[3];
        }
    }
    bf16x4 o;
    o[0] = (bf16_t)fmaxf(a0, 0.f);
    o[1] = (bf16_t)fmaxf(a1, 0.f);
    o[2] = (bf16_t)fmaxf(a2, 0.f);
    o[3] = (bf16_t)fmaxf(a3, 0.f);
    *reinterpret_cast<bf16x4*>(h + (size_t)r * HD + lane * 4) = o;
}

// z[r,:] = sum_e val * z0[col,:]; one wave per row, D=64.
// 4 edge-subgroups of 16 lanes; each subgroup gathers a 64-feature row as
// 16 lanes x bf16x4 (8 B/lane). Edge pairs LDS-staged like spmm_h.
// Cross-subgroup reduce via shfl_xor(16/32).
__global__ __launch_bounds__(256) void spmm_z_kernel(const int* __restrict__ deg,
                                                     const int2* __restrict__ sedge,
                                                     const bf16_t* __restrict__ z0,
                                                     float* __restrict__ z_out,
                                                     bf16_t* __restrict__ z_b) {
    int wv = threadIdx.x >> 6;
    int lane = threadIdx.x & 63;
    int r = blockIdx.x * 4 + wv;
    int sub = lane >> 4;   // 0..3: edge subgroup
    int fl = lane & 15;    // features fl*4 .. fl*4+3
    int nd = deg[r];
    int base = r * BCAP;
    __shared__ int2 ecS[4][64];
    float a0 = 0.f, a1 = 0.f, a2 = 0.f, a3 = 0.f;
    for (int e0 = 0; e0 < nd; e0 += 64) {
        int rem = nd - e0;
        if (rem > 64) rem = 64;
        if (lane < rem) ecS[wv][lane] = sedge[base + e0 + lane];
#pragma unroll 4
        for (int e = sub; e < rem; e += 4) {
            int c = ecS[wv][e].x;
            float v = __int_as_float(ecS[wv][e].y);
            bf16x4 zv = *reinterpret_cast<const bf16x4*>(z0 + (size_t)c * DD + fl * 4);
            a0 += v * (float)zv[0];
            a1 += v * (float)zv[1];
            a2 += v * (float)zv[2];
            a3 += v * (float)zv[3];
        }
    }
    a0 += __shfl_xor(a0, 16); a0 += __shfl_xor(a0, 32);
    a1 += __shfl_xor(a1, 16); a1 += __shfl_xor(a1, 32);
    a2 += __shfl_xor(a2, 16); a2 += __shfl_xor(a2, 32);
    a3 += __shfl_xor(a3, 16); a3 += __shfl_xor(a3, 32);
    if (sub == 0) {
        f32x4 o = {a0, a1, a2, a3};
        *reinterpret_cast<f32x4*>(z_out + (size_t)r * DD + fl * 4) = o;
        bf16x4 ob;
        ob[0] = (bf16_t)a0; ob[1] = (bf16_t)a1; ob[2] = (bf16_t)a2; ob[3] = (bf16_t)a3;
        *reinterpret_cast<bf16x4*>(z_b + (size_t)r * DD + fl * 4) = ob;
    }
}

// ---------------- MFMA GEMM: C[M,N] = A[M,K] @ Bt[N,K]^T (+bias) ----------------
// ACT: 0 = none(+bias), direct stores. 2 = sigmoid, LDS-transposed float4 stores
//      (ACT==2 requires NT==4).
// MW = m-frags per wave, NT = n-frags per block. block = 256 thr (4 waves);
// block tile (64*MW)m x (16*NT)n. GEMM1 uses NT=16 so the whole N=256 is
// covered by one block column -> A is read ONCE from HBM instead of 4x.
// ACT==2 uses a column-fastest grid (blockIdx.x = N band) so concurrent blocks
// sweep full rows of the 268 MB output (stores spread over all HBM channels).
template <int ACT, typename OutT, int MW, int NT>
__global__ __launch_bounds__(256) void gemm_bt(const bf16_t* __restrict__ A,
                                               const bf16_t* __restrict__ Bt,
                                               const float* __restrict__ bias,
                                               OutT* __restrict__ C,
                                               int M, int N, int K) {
    int wave = threadIdx.x >> 6;
    int lane = threadIdx.x & 63;
    int lr = lane & 15;   // row-in-tile for A / col for B,D
    int lq = lane >> 4;   // quad
    int bm = (ACT == 2) ? blockIdx.y : blockIdx.x;
    int bn = (ACT == 2) ? blockIdx.x : blockIdx.y;
    int mblk = bm * (64 * MW);
    int m0 = mblk + wave * (16 * MW);
    int n0 = bn * (16 * NT);

    f32x4 acc[MW][NT];
#pragma unroll
    for (int i = 0; i < MW; i++)
#pragma unroll
        for (int t = 0; t < NT; t++) acc[i][t] = {0.f, 0.f, 0.f, 0.f};

    const bf16_t* Abase = A + (size_t)(m0 + lr) * K + lq * 8;
    const bf16_t* Bbase = Bt + (size_t)(n0 + lr) * K + lq * 8;

    for (int k0 = 0; k0 < K; k0 += 32) {
        bf16x8 a[MW];
#pragma unroll
        for (int i = 0; i < MW; i++)
            a[i] = *reinterpret_cast<const bf16x8*>(Abase + (size_t)i * 16 * K + k0);
#pragma unroll
        for (int t = 0; t < NT; t++) {
            bf16x8 b = *reinterpret_cast<const bf16x8*>(Bbase + (size_t)t * 16 * K + k0);
#pragma unroll
            for (int i = 0; i < MW; i++)
                acc[i][t] = __builtin_amdgcn_mfma_f32_16x16x32_bf16(a[i], b, acc[i][t], 0, 0, 0);
        }
    }

    if (ACT == 2) {
        // Per-wave private LDS transpose: wave owns rows [wave*16*MW, +16*MW).
        // No __syncthreads needed (each wave reads only what it wrote).
        __shared__ float ldsT[256 / 64 * 16 * MW][65];  // [block rows][64+1 pad]
        int rbase = wave * 16 * MW;
#pragma unroll
        for (int i = 0; i < MW; i++)
#pragma unroll
            for (int t = 0; t < 4; t++)
#pragma unroll
                for (int r = 0; r < 4; r++) {
                    float v = acc[i][t][r];
                    v = 1.f / (1.f + __expf(-v));
                    ldsT[rbase + i * 16 + lq * 4 + r][t * 16 + lr] = v;
                }
        // read back row-major: each inst covers 4 rows x 64 cols (float4/lane)
        int c4 = (lane & 15) * 4;
        int rr = lane >> 4;  // 0..3
#pragma unroll
        for (int j = 0; j < 4 * MW; j++) {
            int row_l = rbase + j * 4 + rr;
            f32x4 v = *reinterpret_cast<const f32x4*>(&ldsT[row_l][c4]);
            size_t gaddr = (size_t)(mblk + row_l) * N + n0 + c4;
            *reinterpret_cast<f32x4*>(&C[gaddr]) = v;
        }
    } else {
#pragma unroll
        for (int i = 0; i < MW; i++) {
#pragma unroll
            for (int t = 0; t < NT; t++) {
                int col = n0 + t * 16 + lr;
                float bv = bias ? bias[col] : 0.f;
#pragma unroll
                for (int r = 0; r < 4; r++) {
                    int row = m0 + i * 16 + lq * 4 + r;
                    C[(size_t)row * N + col] = (OutT)(acc[i][t][r] + bv);
                }
            }
        }
    }
}

// ---------------- launch ----------------

extern "C" void kernel_launch(void* const* d_in, const int* in_sizes, int n_in,
                              void* d_out, int out_size, void* d_ws, size_t ws_size,
                              hipStream_t stream) {
    const float* x   = (const float*)d_in[0];
    const int* rows  = (const int*)d_in[1];
    const int* cols  = (const int*)d_in[2];
    const float* vals = (const float*)d_in[3];
    const float* W1  = (const float*)d_in[4];
    const float* b1  = (const float*)d_in[5];
    const float* W2  = (const float*)d_in[6];
    const float* b2  = (const float*)d_in[7];

    float* out_z   = (float*)d_out;                       // [8192,64]
    float* out_adj = out_z + (size_t)NN * DD;             // [8192,8192]

    char* ws = (char*)d_ws;
    size_t off = 0;
    auto alloc = [&](size_t bytes) { void* p = ws + off; off += (bytes + 255) & ~(size_t)255; return p; };
    bf16_t* x_b   = (bf16_t*)alloc((size_t)NN * FIN * 2);    // 8 MB
    bf16_t* w1t   = (bf16_t*)alloc((size_t)HD * FIN * 2);    // 256 KB  [H,FIN]
    bf16_t* w2t   = (bf16_t*)alloc((size_t)DD * HD * 2);     // 32 KB   [D,H]
    bf16_t* h0    = (bf16_t*)alloc((size_t)NN * HD * 2);     // 4 MB  (x@W1+b1, bf16)
    bf16_t* h_b   = (bf16_t*)alloc((size_t)NN * HD * 2);     // 4 MB  (relu(spmm), bf16)
    bf16_t* z0    = (bf16_t*)alloc((size_t)NN * DD * 2);     // 1 MB  (h@W2+b2, bf16)
    bf16_t* z_b   = (bf16_t*)alloc((size_t)NN * DD * 2);     // 1 MB  (z, bf16)
    int* deg      = (int*)alloc((size_t)NN * 4);             // 32 KB
    int2* sedge   = (int2*)alloc((size_t)NN * BCAP * 8);     // 8 MB  bucketed (col,val) pairs

    // prep: cast x, transpose W1/W2, zero deg
    prep_kernel<<<4096 + 512 + 64 + 32, 256, 0, stream>>>(x, x_b, W1, w1t, W2, w2t, deg);

    // bucket scatter (fused 8 B (col,val) stores)
    scatter_edges<<<NE / 256, 256, 0, stream>>>(rows, cols, vals, deg, sedge);

    // GEMM1: h0 = x @ W1 + b1  (bf16 out)  block tile 64m x 256n: A read once
    gemm_bt<0, bf16_t, 1, 16><<<dim3(NN / 64, 1), 256, 0, stream>>>(x_b, w1t, b1, h0, NN, HD, FIN);

    // SpMM1 + relu -> bf16  (wave-per-row, LDS edge staging)
    spmm_h_kernel<<<NN / 4, 256, 0, stream>>>(deg, sedge, h0, h_b);

    // GEMM2: z0 = h @ W2 + b2  (bf16 out)
    gemm_bt<0, bf16_t, 1, 4><<<dim3(NN / 64, 1), 256, 0, stream>>>(h_b, w2t, b2, z0, NN, DD, HD);

    // SpMM2 -> z (fp32 out) + bf16 copy  (LDS edge staging)
    spmm_z_kernel<<<NN / 4, 256, 0, stream>>>(deg, sedge, z0, out_z, z_b);

    // GEMM3: adj_rec = sigmoid(z @ z^T)  tile 128x64, col-fastest grid
    gemm_bt<2, float, 2, 4><<<dim3(NN / 64, NN / 128), 256, 0, stream>>>(z_b, z_b, nullptr, out_adj, NN, NN, DD);
}

// Round 4
// 368.322 us; speedup vs baseline: 1.0949x; 1.0949x over previous
//
#include <hip/hip_runtime.h>
#include <hip/hip_bf16.h>

#define NN 8192      // nodes
#define FIN 512      // in features
#define HD 256       // hidden
#define DD 64        // embedding
#define NE 262144    // edges
#define BCAP 128     // fixed bucket capacity per row (max degree ~60 for this graph; 17-sigma margin)

typedef __bf16 bf16_t;
typedef __bf16 bf16x8 __attribute__((ext_vector_type(8)));
typedef __bf16 bf16x4 __attribute__((ext_vector_type(4)));
typedef float f32x4 __attribute__((ext_vector_type(4)));

// ---------------- fused prep: cast x, transpose W1/W2, zero degree counters ----------------
// grid = 4096 (x) + 512 (W1) + 64 (W2) + 32 (zero deg) blocks of 256
__global__ __launch_bounds__(256) void prep_kernel(const float* __restrict__ x, bf16_t* __restrict__ x_b,
                                                   const float* __restrict__ W1, bf16_t* __restrict__ w1t,
                                                   const float* __restrict__ W2, bf16_t* __restrict__ w2t,
                                                   int* __restrict__ deg) {
    int b = blockIdx.x;
    if (b < 4096) {
        int i = (b * 256 + threadIdx.x) * 4;
        float4 v = *reinterpret_cast<const float4*>(x + i);
        x_b[i + 0] = (bf16_t)v.x;
        x_b[i + 1] = (bf16_t)v.y;
        x_b[i + 2] = (bf16_t)v.z;
        x_b[i + 3] = (bf16_t)v.w;
    } else if (b < 4096 + 512) {
        // W1 [FIN=512, HD=256] -> w1t [HD, FIN];  o = c*512 + r
        int o = (b - 4096) * 256 + threadIdx.x;
        int r = o & 511;
        int c = o >> 9;
        w1t[o] = (bf16_t)W1[r * HD + c];
    } else if (b < 4096 + 512 + 64) {
        // W2 [HD=256, DD=64] -> w2t [DD, HD];  o = c*256 + r
        int o = (b - 4096 - 512) * 256 + threadIdx.x;
        int r = o & 255;
        int c = o >> 8;
        w2t[o] = (bf16_t)W2[r * DD + c];
    } else {
        int o = (b - 4096 - 512 - 64) * 256 + threadIdx.x;
        deg[o] = 0;
    }
}

// ---------------- bucket build (no CSR: fixed stride BCAP per row) ----------------
// (col, val) fused into one int2 -> ONE random 8 B store per edge.

__global__ void scatter_edges(const int* __restrict__ rows, const int* __restrict__ cols,
                              const float* __restrict__ vals,
                              int* __restrict__ deg, int2* __restrict__ sedge) {
    int e = blockIdx.x * blockDim.x + threadIdx.x;
    if (e < NE) {
        int r = rows[e];
        int p = atomicAdd(&deg[r], 1);
        int2 pk;
        pk.x = cols[e];
        pk.y = __float_as_int(vals[e]);
        sedge[r * BCAP + p] = pk;
    }
}

// ---------------- SpMM ----------------

// h[r,:] = relu(sum_e val * h0[col,:]); one WAVE per row (4 rows/block).
// Wave covers all 256 features as 64 lanes x bf16x4 (8 B/lane). Edge (col,val)
// pairs staged into per-wave LDS with one coalesced int2 load; gather loop
// unrolled over independent addresses. Broadcast LDS reads are conflict-free.
__global__ __launch_bounds__(256) void spmm_h_kernel(const int* __restrict__ deg,
                                                     const int2* __restrict__ sedge,
                                                     const bf16_t* __restrict__ h0,
                                                     bf16_t* __restrict__ h) {
    int wv = threadIdx.x >> 6;
    int lane = threadIdx.x & 63;
    int r = blockIdx.x * 4 + wv;
    int nd = deg[r];
    int base = r * BCAP;
    __shared__ int2 ecS[4][64];
    float a0 = 0.f, a1 = 0.f, a2 = 0.f, a3 = 0.f;
    for (int e0 = 0; e0 < nd; e0 += 64) {
        int rem = nd - e0;
        if (rem > 64) rem = 64;
        if (lane < rem) ecS[wv][lane] = sedge[base + e0 + lane];
        // wave-private LDS: compiler orders ds_write->ds_read via lgkmcnt
#pragma unroll 4
        for (int e = 0; e < rem; e++) {
            int c = ecS[wv][e].x;
            float v = __int_as_float(ecS[wv][e].y);
            bf16x4 hv = *reinterpret_cast<const bf16x4*>(h0 + (size_t)c * HD + lane * 4);
            a0 += v * (float)hv[0];
            a1 += v * (float)hv[1];
            a2 += v * (float)hv[2];
            a3 += v * (float)hv[3];
        }
    }
    bf16x4 o;
    o[0] = (bf16_t)fmaxf(a0, 0.f);
    o[1] = (bf16_t)fmaxf(a1, 0.f);
    o[2] = (bf16_t)fmaxf(a2, 0.f);
    o[3] = (bf16_t)fmaxf(a3, 0.f);
    *reinterpret_cast<bf16x4*>(h + (size_t)r * HD + lane * 4) = o;
}

// z[r,:] = sum_e val * z0[col,:]; one wave per row, D=64.
// 4 edge-subgroups of 16 lanes; each subgroup gathers a 64-feature row as
// 16 lanes x bf16x4 (8 B/lane). Cross-subgroup reduce via shfl_xor(16/32).
__global__ __launch_bounds__(256) void spmm_z_kernel(const int* __restrict__ deg,
                                                     const int2* __restrict__ sedge,
                                                     const bf16_t* __restrict__ z0,
                                                     float* __restrict__ z_out,
                                                     bf16_t* __restrict__ z_b) {
    int wv = threadIdx.x >> 6;
    int lane = threadIdx.x & 63;
    int r = blockIdx.x * 4 + wv;
    int sub = lane >> 4;   // 0..3: edge subgroup
    int fl = lane & 15;    // features fl*4 .. fl*4+3
    int nd = deg[r];
    int base = r * BCAP;
    __shared__ int2 ecS[4][64];
    float a0 = 0.f, a1 = 0.f, a2 = 0.f, a3 = 0.f;
    for (int e0 = 0; e0 < nd; e0 += 64) {
        int rem = nd - e0;
        if (rem > 64) rem = 64;
        if (lane < rem) ecS[wv][lane] = sedge[base + e0 + lane];
#pragma unroll 4
        for (int e = sub; e < rem; e += 4) {
            int c = ecS[wv][e].x;
            float v = __int_as_float(ecS[wv][e].y);
            bf16x4 zv = *reinterpret_cast<const bf16x4*>(z0 + (size_t)c * DD + fl * 4);
            a0 += v * (float)zv[0];
            a1 += v * (float)zv[1];
            a2 += v * (float)zv[2];
            a3 += v * (float)zv[3];
        }
    }
    a0 += __shfl_xor(a0, 16); a0 += __shfl_xor(a0, 32);
    a1 += __shfl_xor(a1, 16); a1 += __shfl_xor(a1, 32);
    a2 += __shfl_xor(a2, 16); a2 += __shfl_xor(a2, 32);
    a3 += __shfl_xor(a3, 16); a3 += __shfl_xor(a3, 32);
    if (sub == 0) {
        f32x4 o = {a0, a1, a2, a3};
        *reinterpret_cast<f32x4*>(z_out + (size_t)r * DD + fl * 4) = o;
        bf16x4 ob;
        ob[0] = (bf16_t)a0; ob[1] = (bf16_t)a1; ob[2] = (bf16_t)a2; ob[3] = (bf16_t)a3;
        *reinterpret_cast<bf16x4*>(z_b + (size_t)r * DD + fl * 4) = ob;
    }
}

// ---------------- MFMA GEMM: C[M,N] = A[M,K] @ Bt[N,K]^T (+bias) ----------------
// ACT: 0 = none(+bias), direct stores. 2 = sigmoid, LDS-transposed float4 stores
//      (ACT==2 requires NT==4).
// MW = m-frags per wave, NT = n-frags per block. block = 256 thr (4 waves);
// block tile (64*MW)m x (16*NT)n.
// ACT==2: column-fastest grid (blockIdx.x = N band) so concurrent blocks sweep
// full rows of the 268 MB output. LDS transpose is PER-WAVE PER-FRAGMENT
// ([4][16][65] = 16.6 KB, ping-ponged over MW) instead of a whole-block-tile
// buffer (133 KB) -> occupancy 1 -> ~6 blocks/CU; this kernel is nearly pure
// epilogue (K=64: 2 k-steps), so store/exp throughput needs the TLP.
template <int ACT, typename OutT, int MW, int NT>
__global__ __launch_bounds__(256) void gemm_bt(const bf16_t* __restrict__ A,
                                               const bf16_t* __restrict__ Bt,
                                               const float* __restrict__ bias,
                                               OutT* __restrict__ C,
                                               int M, int N, int K) {
    int wave = threadIdx.x >> 6;
    int lane = threadIdx.x & 63;
    int lr = lane & 15;   // row-in-tile for A / col for B,D
    int lq = lane >> 4;   // quad
    int bm = (ACT == 2) ? blockIdx.y : blockIdx.x;
    int bn = (ACT == 2) ? blockIdx.x : blockIdx.y;
    int mblk = bm * (64 * MW);
    int m0 = mblk + wave * (16 * MW);
    int n0 = bn * (16 * NT);

    f32x4 acc[MW][NT];
#pragma unroll
    for (int i = 0; i < MW; i++)
#pragma unroll
        for (int t = 0; t < NT; t++) acc[i][t] = {0.f, 0.f, 0.f, 0.f};

    const bf16_t* Abase = A + (size_t)(m0 + lr) * K + lq * 8;
    const bf16_t* Bbase = Bt + (size_t)(n0 + lr) * K + lq * 8;

    for (int k0 = 0; k0 < K; k0 += 32) {
        bf16x8 a[MW];
#pragma unroll
        for (int i = 0; i < MW; i++)
            a[i] = *reinterpret_cast<const bf16x8*>(Abase + (size_t)i * 16 * K + k0);
#pragma unroll
        for (int t = 0; t < NT; t++) {
            bf16x8 b = *reinterpret_cast<const bf16x8*>(Bbase + (size_t)t * 16 * K + k0);
#pragma unroll
            for (int i = 0; i < MW; i++)
                acc[i][t] = __builtin_amdgcn_mfma_f32_16x16x32_bf16(a[i], b, acc[i][t], 0, 0, 0);
        }
    }

    if (ACT == 2) {
        // Per-wave, per-16-row-fragment LDS transpose (ping-pong over i).
        // Wave-private slice: no __syncthreads; same-wave DS ordering handles
        // the WAR between iteration i's reads and i+1's writes.
        __shared__ float ldsT[4][16][65];
        int c4 = (lane & 15) * 4;
        int rr = lane >> 4;  // 0..3
#pragma unroll
        for (int i = 0; i < MW; i++) {
#pragma unroll
            for (int t = 0; t < 4; t++)
#pragma unroll
                for (int r = 0; r < 4; r++) {
                    float v = acc[i][t][r];
                    v = 1.f / (1.f + __expf(-v));
                    ldsT[wave][lq * 4 + r][t * 16 + lr] = v;
                }
            // read back row-major: each inst covers 4 rows x 64 cols (float4/lane)
#pragma unroll
            for (int j = 0; j < 4; j++) {
                int row_l = j * 4 + rr;  // 0..15 within this fragment
                f32x4 v = *reinterpret_cast<const f32x4*>(&ldsT[wave][row_l][c4]);
                size_t grow = (size_t)(m0 + i * 16 + row_l);
                *reinterpret_cast<f32x4*>(&C[grow * N + n0 + c4]) = v;
            }
        }
    } else {
#pragma unroll
        for (int i = 0; i < MW; i++) {
#pragma unroll
            for (int t = 0; t < NT; t++) {
                int col = n0 + t * 16 + lr;
                float bv = bias ? bias[col] : 0.f;
#pragma unroll
                for (int r = 0; r < 4; r++) {
                    int row = m0 + i * 16 + lq * 4 + r;
                    C[(size_t)row * N + col] = (OutT)(acc[i][t][r] + bv);
                }
            }
        }
    }
}

// ---------------- launch ----------------

extern "C" void kernel_launch(void* const* d_in, const int* in_sizes, int n_in,
                              void* d_out, int out_size, void* d_ws, size_t ws_size,
                              hipStream_t stream) {
    const float* x   = (const float*)d_in[0];
    const int* rows  = (const int*)d_in[1];
    const int* cols  = (const int*)d_in[2];
    const float* vals = (const float*)d_in[3];
    const float* W1  = (const float*)d_in[4];
    const float* b1  = (const float*)d_in[5];
    const float* W2  = (const float*)d_in[6];
    const float* b2  = (const float*)d_in[7];

    float* out_z   = (float*)d_out;                       // [8192,64]
    float* out_adj = out_z + (size_t)NN * DD;             // [8192,8192]

    char* ws = (char*)d_ws;
    size_t off = 0;
    auto alloc = [&](size_t bytes) { void* p = ws + off; off += (bytes + 255) & ~(size_t)255; return p; };
    bf16_t* x_b   = (bf16_t*)alloc((size_t)NN * FIN * 2);    // 8 MB
    bf16_t* w1t   = (bf16_t*)alloc((size_t)HD * FIN * 2);    // 256 KB  [H,FIN]
    bf16_t* w2t   = (bf16_t*)alloc((size_t)DD * HD * 2);     // 32 KB   [D,H]
    bf16_t* h0    = (bf16_t*)alloc((size_t)NN * HD * 2);     // 4 MB  (x@W1+b1, bf16)
    bf16_t* h_b   = (bf16_t*)alloc((size_t)NN * HD * 2);     // 4 MB  (relu(spmm), bf16)
    bf16_t* z0    = (bf16_t*)alloc((size_t)NN * DD * 2);     // 1 MB  (h@W2+b2, bf16)
    bf16_t* z_b   = (bf16_t*)alloc((size_t)NN * DD * 2);     // 1 MB  (z, bf16)
    int* deg      = (int*)alloc((size_t)NN * 4);             // 32 KB
    int2* sedge   = (int2*)alloc((size_t)NN * BCAP * 8);     // 8 MB  bucketed (col,val) pairs

    // prep: cast x, transpose W1/W2, zero deg
    prep_kernel<<<4096 + 512 + 64 + 32, 256, 0, stream>>>(x, x_b, W1, w1t, W2, w2t, deg);

    // bucket scatter (fused 8 B (col,val) stores)
    scatter_edges<<<NE / 256, 256, 0, stream>>>(rows, cols, vals, deg, sedge);

    // GEMM1: h0 = x @ W1 + b1  (bf16 out)  64x64 tile, 512 blocks (2/CU)
    gemm_bt<0, bf16_t, 1, 4><<<dim3(NN / 64, HD / 64), 256, 0, stream>>>(x_b, w1t, b1, h0, NN, HD, FIN);

    // SpMM1 + relu -> bf16  (wave-per-row, LDS edge staging)
    spmm_h_kernel<<<NN / 4, 256, 0, stream>>>(deg, sedge, h0, h_b);

    // GEMM2: z0 = h @ W2 + b2  (bf16 out)
    gemm_bt<0, bf16_t, 1, 4><<<dim3(NN / 64, DD / 64), 256, 0, stream>>>(h_b, w2t, b2, z0, NN, DD, HD);

    // SpMM2 -> z (fp32 out) + bf16 copy  (LDS edge staging)
    spmm_z_kernel<<<NN / 4, 256, 0, stream>>>(deg, sedge, z0, out_z, z_b);

    // GEMM3: adj_rec = sigmoid(z @ z^T)  tile 128x64, col-fastest grid,
    // small per-wave LDS epilogue (occupancy fix)
    gemm_bt<2, float, 2, 4><<<dim3(NN / 64, NN / 128), 256, 0, stream>>>(z_b, z_b, nullptr, out_adj, NN, NN, DD);
}